// Round 5
// baseline (214.085 us; speedup 1.0000x reference)
//
#include <hip/hip_runtime.h>

// MoE dense: N=16384, D=256, E=8, H=128.
// R5: revert to split stage1/stage2 (R4 fusion was grid-limited to 1 block/CU,
// 120us @ 11% occ). New: (a) coalesced LDS-tile transposes in prep (was 1KB-
// stride gathers), (b) split-K stage2: 4 K-splits, 128x128 tiles, 1024 blocks
// = 4 blocks/CU, fp32 atomicAdd combine onto memset-zeroed out.
// Workspace (80,437,248 B - known to fit from R2/R3):
//   xb   [16384][288] bf16 @ 0         (col 256 = 1.0 -> bias, 257..=0)
//   w1t  [8][256][288] bf16 @ 9437184  (W1^T per expert, col 256 = b1)
//   wg1t [128][288] bf16 @ 10616832    (Wg1^T, col 256 = bg1)
//   w2t  [256][2080] bf16 @ 10690560   (stacked W2^T; cols 2048+e = b2[e][d])
//   g    [16384][8] f32 @ 11755520
//   hw   [16384][2080] bf16 @ 12279808 (e*256+h = g*relu(.); 2048+e = g)

typedef unsigned short USH;
typedef float f32x4 __attribute__((ext_vector_type(4)));
typedef __bf16 bf16x8 __attribute__((ext_vector_type(8)));

#define AS1 __attribute__((address_space(1)))
#define AS3 __attribute__((address_space(3)))

__device__ __forceinline__ USH f2bf(float f) {
  unsigned int u = __float_as_uint(f);
  u += 0x7fffu + ((u >> 16) & 1u);   // RNE
  return (USH)(u >> 16);
}

__device__ __forceinline__ void gl2lds16(const void* g, void* l) {
  __builtin_amdgcn_global_load_lds((AS1 const void*)g, (AS3 void*)l, 16, 0, 0);
}

// ---------------- prep: cast/pad/transpose, all coalesced ----------------
// blocks: [0,2304) xb | [2304,2448) wg1t | [2448,2576) w1t-T | [2576,2584)
// w1t-bias | [2584,2712) w2t-T | 2712 w2t-bias

__global__ __launch_bounds__(256) void k_prep(
    const float* __restrict__ x,
    const float* __restrict__ Wg1, const float* __restrict__ bg1,
    const float* __restrict__ W1,  const float* __restrict__ b1,
    const float* __restrict__ W2,  const float* __restrict__ b2,
    USH* __restrict__ xb, USH* __restrict__ wg1t,
    USH* __restrict__ w1t, USH* __restrict__ w2t) {
  __shared__ float T[64][65];   // transpose tile (+1 pad: 2-way max = free)
  int b = blockIdx.x, tid = threadIdx.x;

  if (b < 2304) {               // xb: coalesced cast + pad
    int idx = b * 256 + tid;
    int n = idx / 36, gc = idx % 36;
    int c0 = gc * 8;
    USH v[8];
#pragma unroll
    for (int k = 0; k < 8; ++k) {
      int c = c0 + k;
      float f = (c < 256) ? x[(size_t)n * 256 + c] : (c == 256 ? 1.0f : 0.0f);
      v[k] = f2bf(f);
    }
    *(uint4*)(xb + (size_t)idx * 8) = *(const uint4*)v;
  } else if (b < 2448) {        // wg1t gather (tiny: 128x288)
    int idx = (b - 2304) * 256 + tid;
    int h = idx / 288, c = idx % 288;
    float v = 0.0f;
    if (c < 256) v = Wg1[(size_t)c * 128 + h];
    else if (c == 256) v = bg1[h];
    wg1t[idx] = f2bf(v);
  } else if (b < 2576) {        // w1t[e][h][c] = W1[e][c][h], 64x64 LDS tiles
    int bp = b - 2448;
    int e = bp >> 4, tl = bp & 15;
    int c0 = (tl >> 2) * 64, h0 = (tl & 3) * 64;
    const float* src = W1 + (size_t)e * 65536;
#pragma unroll
    for (int p = 0; p < 4; ++p) {
      int r = p * 16 + (tid >> 4), d4 = (tid & 15) * 4;
      float4 v = *(const float4*)(src + (size_t)(c0 + r) * 256 + h0 + d4);
      T[r][d4] = v.x; T[r][d4 + 1] = v.y; T[r][d4 + 2] = v.z; T[r][d4 + 3] = v.w;
    }
    __syncthreads();
#pragma unroll
    for (int p = 0; p < 4; ++p) {
      int hr = p * 16 + (tid >> 4), c4 = (tid & 15) * 4;
      USH w[4];
#pragma unroll
      for (int j = 0; j < 4; ++j) w[j] = f2bf(T[c4 + j][hr]);
      *(uint2*)(w1t + (size_t)e * 73728 + (size_t)(h0 + hr) * 288 + c0 + c4) = *(const uint2*)w;
    }
  } else if (b < 2584) {        // w1t bias cols 256..287
    int e = b - 2576;
    size_t base = (size_t)e * 73728 + (size_t)tid * 288 + 256;
    USH w[4] = {f2bf(b1[e * 256 + tid]), 0, 0, 0};
    *(uint2*)(w1t + base) = *(const uint2*)w;
    USH z[4] = {0, 0, 0, 0};
#pragma unroll
    for (int p = 1; p < 8; ++p) *(uint2*)(w1t + base + p * 4) = *(const uint2*)z;
  } else if (b < 2712) {        // w2t[d][e*256+h] = W2[e][h][d], 64x64 tiles
    int bp = b - 2584;
    int e = bp >> 4, tl = bp & 15;
    int h0 = (tl >> 2) * 64, d0 = (tl & 3) * 64;
    const float* src = W2 + (size_t)e * 65536;
#pragma unroll
    for (int p = 0; p < 4; ++p) {
      int r = p * 16 + (tid >> 4), d4 = (tid & 15) * 4;
      float4 v = *(const float4*)(src + (size_t)(h0 + r) * 256 + d0 + d4);
      T[r][d4] = v.x; T[r][d4 + 1] = v.y; T[r][d4 + 2] = v.z; T[r][d4 + 3] = v.w;
    }
    __syncthreads();
#pragma unroll
    for (int p = 0; p < 4; ++p) {
      int dr = p * 16 + (tid >> 4), h4 = (tid & 15) * 4;
      USH w[4];
#pragma unroll
      for (int j = 0; j < 4; ++j) w[j] = f2bf(T[h4 + j][dr]);
      *(uint2*)(w2t + (size_t)(d0 + dr) * 2080 + e * 256 + h0 + h4) = *(const uint2*)w;
    }
  } else {                      // w2t bias cols 2048..2079 (1 block, tid = d)
    size_t base = (size_t)tid * 2080 + 2048;
#pragma unroll
    for (int p = 0; p < 8; ++p) {
      USH w[4];
#pragma unroll
      for (int j = 0; j < 4; ++j) {
        int e = p * 4 + j;
        w[j] = (e < 8) ? f2bf(b2[e * 256 + tid]) : (USH)0;
      }
      *(uint2*)(w2t + base + p * 4) = *(const uint2*)w;
    }
  }
}

// ---------------- gate: g = softmax(relu(x@Wg1+bg1)@Wg2+bg2) ----------------

__global__ __launch_bounds__(256) void k_gate(const USH* __restrict__ xb,
                                              const USH* __restrict__ wg1t,
                                              const float* __restrict__ wg2,
                                              const float* __restrict__ bg2,
                                              float* __restrict__ g,
                                              USH* __restrict__ hw) {
  __shared__ __align__(16) USH As[64 * 32];
  __shared__ __align__(16) USH Bs[128 * 32];
  __shared__ float hg[64 * 129];
  __shared__ float w2s[128 * 8];
  __shared__ float b2s[8];
  __shared__ float lg[64 * 8];

  int tid = threadIdx.x;
  int wave = tid >> 6, lane = tid & 63;
  int quad = lane >> 4, l16 = lane & 15;
  int rowBase = blockIdx.x * 64;

  for (int t = tid; t < 1024; t += 256) w2s[t] = wg2[t];
  if (tid < 8) b2s[tid] = bg2[tid];

  f32x4 acc[8] = {};
  for (int kt = 0; kt < 9; ++kt) {
    int kb = kt * 32;
    {
      int r = tid >> 2, kc = (tid & 3) * 8;
      gl2lds16(xb + (size_t)(rowBase + r) * 288 + kb + kc, As + (size_t)tid * 8);
    }
#pragma unroll
    for (int c = 0; c < 2; ++c) {
      int i = c * 256 + tid;
      int r = i >> 2, kc = (i & 3) * 8;
      gl2lds16(wg1t + (size_t)r * 288 + kb + kc, Bs + (size_t)i * 8);
    }
    __syncthreads();
    bf16x8 av = *(const bf16x8*)(As + (wave * 16 + l16) * 32 + quad * 8);
#pragma unroll
    for (int j = 0; j < 8; ++j) {
      bf16x8 bv = *(const bf16x8*)(Bs + (j * 16 + l16) * 32 + quad * 8);
      acc[j] = __builtin_amdgcn_mfma_f32_16x16x32_bf16(av, bv, acc[j], 0, 0, 0);
    }
    __syncthreads();
  }

#pragma unroll
  for (int j = 0; j < 8; ++j)
#pragma unroll
    for (int r = 0; r < 4; ++r) {
      int row = wave * 16 + quad * 4 + r;
      int col = j * 16 + l16;
      hg[row * 129 + col] = fmaxf(acc[j][r], 0.0f);
    }
  __syncthreads();

  {
    int row = tid >> 2, p = tid & 3;
    float s0 = b2s[p * 2], s1 = b2s[p * 2 + 1];
    for (int k = 0; k < 128; ++k) {
      float h = hg[row * 129 + k];
      s0 += h * w2s[k * 8 + p * 2];
      s1 += h * w2s[k * 8 + p * 2 + 1];
    }
    lg[row * 8 + p * 2] = s0;
    lg[row * 8 + p * 2 + 1] = s1;
  }
  __syncthreads();

  if (tid < 64) {
    float l[8];
    float m = -1e30f;
#pragma unroll
    for (int e = 0; e < 8; ++e) { l[e] = lg[tid * 8 + e]; m = fmaxf(m, l[e]); }
    float s = 0.0f;
#pragma unroll
    for (int e = 0; e < 8; ++e) { l[e] = expf(l[e] - m); s += l[e]; }
    float inv = 1.0f / s;
    size_t grow = rowBase + tid;
#pragma unroll
    for (int e = 0; e < 8; ++e) {
      float ge = l[e] * inv;
      g[grow * 8 + e] = ge;
      hw[grow * 2080 + 2048 + e] = f2bf(ge);
    }
#pragma unroll
    for (int z = 0; z < 24; ++z) hw[grow * 2080 + 2056 + z] = 0;
  }
}

// ---------------- stage 1: hw[:, e*256+h] = g[:,e]*relu(x@W1[e]+b1[e]) ----------------

__global__ __launch_bounds__(256) void k_stage1(const USH* __restrict__ xb,
                                                const USH* __restrict__ w1t,
                                                const float* __restrict__ g,
                                                USH* __restrict__ hw) {
  __shared__ __align__(16) USH As[128 * 32];
  __shared__ __align__(16) USH Bs[128 * 32];
  __shared__ float gs[128];

  int tid = threadIdx.x;
  int wave = tid >> 6, lane = tid & 63;
  int quad = lane >> 4, l16 = lane & 15;
  int wr = wave >> 1, wc = wave & 1;
  int rowBase = blockIdx.x * 128;
  int colBase = blockIdx.y * 128;
  int e = blockIdx.z;

  if (tid < 128) gs[tid] = g[(size_t)(rowBase + tid) * 8 + e];

  const USH* B = w1t + (size_t)e * 256 * 288;

  f32x4 acc[4][4] = {};
  for (int kt = 0; kt < 9; ++kt) {
    int kb = kt * 32;
#pragma unroll
    for (int c = 0; c < 2; ++c) {
      int i = c * 256 + tid;
      int r = i >> 2, kc = (i & 3) * 8;
      gl2lds16(xb + (size_t)(rowBase + r) * 288 + kb + kc, As + (size_t)i * 8);
      gl2lds16(B + (size_t)(colBase + r) * 288 + kb + kc, Bs + (size_t)i * 8);
    }
    __syncthreads();
    bf16x8 av[4], bv[4];
#pragma unroll
    for (int i = 0; i < 4; ++i)
      av[i] = *(const bf16x8*)(As + (wr * 64 + i * 16 + l16) * 32 + quad * 8);
#pragma unroll
    for (int j = 0; j < 4; ++j)
      bv[j] = *(const bf16x8*)(Bs + (wc * 64 + j * 16 + l16) * 32 + quad * 8);
#pragma unroll
    for (int i = 0; i < 4; ++i)
#pragma unroll
      for (int j = 0; j < 4; ++j)
        acc[i][j] = __builtin_amdgcn_mfma_f32_16x16x32_bf16(av[i], bv[j], acc[i][j], 0, 0, 0);
    __syncthreads();
  }

#pragma unroll
  for (int i = 0; i < 4; ++i) {
#pragma unroll
    for (int r = 0; r < 4; ++r) {
      int rl = wr * 64 + i * 16 + quad * 4 + r;
      float gg = gs[rl];
      size_t grow = (size_t)(rowBase + rl);
#pragma unroll
      for (int j = 0; j < 4; ++j) {
        int col = colBase + wc * 64 + j * 16 + l16;
        float v = fmaxf(acc[i][j][r], 0.0f) * gg;
        hw[grow * 2080 + e * 256 + col] = f2bf(v);
      }
    }
  }
}

// ---------------- stage 2: out += split-K slice of hw @ w2t^T ----------------
// grid (128,2,4): z = K-split {17,16,16,16} ktiles; fp32 atomicAdd combine.

__global__ __launch_bounds__(256) void k_stage2(const USH* __restrict__ hwm,
                                                const USH* __restrict__ w2t,
                                                float* __restrict__ out) {
  __shared__ __align__(16) USH As[128 * 32];
  __shared__ __align__(16) USH Bs[128 * 32];

  int tid = threadIdx.x;
  int wave = tid >> 6, lane = tid & 63;
  int quad = lane >> 4, l16 = lane & 15;
  int wr = wave >> 1, wc = wave & 1;
  int rowBase = blockIdx.x * 128;
  int colBase = blockIdx.y * 128;
  int z = blockIdx.z;
  int kt0 = (z == 0) ? 0 : 17 + (z - 1) * 16;
  int ktn = (z == 0) ? 17 : 16;

  f32x4 acc[4][4] = {};
  for (int kt = kt0; kt < kt0 + ktn; ++kt) {
    int kb = kt * 32;
#pragma unroll
    for (int c = 0; c < 2; ++c) {
      int i = c * 256 + tid;
      int r = i >> 2, kc = (i & 3) * 8;
      gl2lds16(hwm + (size_t)(rowBase + r) * 2080 + kb + kc, As + (size_t)i * 8);
      gl2lds16(w2t + (size_t)(colBase + r) * 2080 + kb + kc, Bs + (size_t)i * 8);
    }
    __syncthreads();
    bf16x8 av[4], bv[4];
#pragma unroll
    for (int i = 0; i < 4; ++i)
      av[i] = *(const bf16x8*)(As + (wr * 64 + i * 16 + l16) * 32 + quad * 8);
#pragma unroll
    for (int j = 0; j < 4; ++j)
      bv[j] = *(const bf16x8*)(Bs + (wc * 64 + j * 16 + l16) * 32 + quad * 8);
#pragma unroll
    for (int i = 0; i < 4; ++i)
#pragma unroll
      for (int j = 0; j < 4; ++j)
        acc[i][j] = __builtin_amdgcn_mfma_f32_16x16x32_bf16(av[i], bv[j], acc[i][j], 0, 0, 0);
    __syncthreads();
  }

#pragma unroll
  for (int i = 0; i < 4; ++i) {
#pragma unroll
    for (int r = 0; r < 4; ++r) {
      int rl = wr * 64 + i * 16 + quad * 4 + r;
      size_t grow = (size_t)(rowBase + rl);
#pragma unroll
      for (int j = 0; j < 4; ++j) {
        int col = colBase + wc * 64 + j * 16 + l16;
        atomicAdd(&out[grow * 256 + col], acc[i][j][r]);
      }
    }
  }
}

// ---------------- launch ----------------

extern "C" void kernel_launch(void* const* d_in, const int* in_sizes, int n_in,
                              void* d_out, int out_size, void* d_ws, size_t ws_size,
                              hipStream_t stream) {
  const float* x   = (const float*)d_in[0];
  const float* Wg1 = (const float*)d_in[1];
  const float* bg1 = (const float*)d_in[2];
  const float* Wg2 = (const float*)d_in[3];
  const float* bg2 = (const float*)d_in[4];
  const float* W1  = (const float*)d_in[5];
  const float* b1  = (const float*)d_in[6];
  const float* W2  = (const float*)d_in[7];
  const float* b2  = (const float*)d_in[8];
  float* out = (float*)d_out;

  char* ws = (char*)d_ws;
  USH*   xb   = (USH*)(ws);
  USH*   w1t  = (USH*)(ws + 9437184);
  USH*   wg1t = (USH*)(ws + 10616832);
  USH*   w2t  = (USH*)(ws + 10690560);
  float* g    = (float*)(ws + 11755520);
  USH*   hw   = (USH*)(ws + 12279808);   // total 80,437,248 B

  hipMemsetAsync(out, 0, (size_t)16384 * 256 * 4, stream);
  hipLaunchKernelGGL(k_prep, dim3(2713), dim3(256), 0, stream,
                     x, Wg1, bg1, W1, b1, W2, b2, xb, wg1t, w1t, w2t);
  hipLaunchKernelGGL(k_gate,   dim3(256),       dim3(256), 0, stream, xb, wg1t, Wg2, bg2, g, hw);
  hipLaunchKernelGGL(k_stage1, dim3(128, 2, 8), dim3(256), 0, stream, xb, w1t, g, hw);
  hipLaunchKernelGGL(k_stage2, dim3(128, 2, 4), dim3(256), 0, stream, hw, w2t, out);
}

// Round 6
// 163.556 us; speedup vs baseline: 1.3089x; 1.3089x over previous
//
#include <hip/hip_runtime.h>

// MoE dense: N=16384, D=256, E=8, H=128.
// R6: (a) stage2 64x64 tiles, 1024 blocks = 4/CU, direct stores (R5 atomics
// regressed: 4x WRITE_SIZE, MfmaUtil 13->8). (b) K=256 everywhere — b1/bg1
// added in fp32 epilogue instead of K-fold (-1 ktile in stage1/gate).
// (c) division-free flat-cast prep (idx/36 was ~burning VALU in 2304 blocks).
// Workspace (79,249,408 B <= 80,437,248 known-OK):
//   xb   [16384][256] bf16 @ 0
//   w1t  [8][256][256] bf16 @ 8388608   (w1t[e][h][c] = W1[e][c][h])
//   wg1t [128][256] bf16 @ 9437184      (wg1t[h][c] = Wg1[c][h])
//   w2t  [256][2080] bf16 @ 9502720     (w2t[d][e*256+h] = W2[e][h][d]; cols 2048+e = b2[e][d])
//   g    [16384][8] f32 @ 10567680
//   hw   [16384][2080] bf16 @ 11091968  (e*256+h = g*relu(.); 2048+e = g; pad 0)

typedef unsigned short USH;
typedef float f32x4 __attribute__((ext_vector_type(4)));
typedef __bf16 bf16x8 __attribute__((ext_vector_type(8)));

#define AS1 __attribute__((address_space(1)))
#define AS3 __attribute__((address_space(3)))

__device__ __forceinline__ USH f2bf(float f) {
  unsigned int u = __float_as_uint(f);
  u += 0x7fffu + ((u >> 16) & 1u);   // RNE
  return (USH)(u >> 16);
}

__device__ __forceinline__ void gl2lds16(const void* g, void* l) {
  __builtin_amdgcn_global_load_lds((AS1 const void*)g, (AS3 void*)l, 16, 0, 0);
}

// ---------------- prep ----------------
// blocks: [0,2048) xb flat cast | [2048,2176) w1t-T | [2176,2184) wg1t-T |
// [2184,2312) w2t-T | 2312 w2t bias cols

__global__ __launch_bounds__(256) void k_prep(
    const float* __restrict__ x,
    const float* __restrict__ Wg1,
    const float* __restrict__ W1,
    const float* __restrict__ W2,  const float* __restrict__ b2,
    USH* __restrict__ xb, USH* __restrict__ wg1t,
    USH* __restrict__ w1t, USH* __restrict__ w2t) {
  __shared__ float T[64][65];   // transpose tile (+1 pad)
  int b = blockIdx.x, tid = threadIdx.x;

  if (b < 2048) {               // xb: flat coalesced cast, 8 elems/thread
    size_t i8 = ((size_t)b * 256 + tid) * 8;
    float4 a = *(const float4*)(x + i8);
    float4 c = *(const float4*)(x + i8 + 4);
    USH v[8];
    v[0] = f2bf(a.x); v[1] = f2bf(a.y); v[2] = f2bf(a.z); v[3] = f2bf(a.w);
    v[4] = f2bf(c.x); v[5] = f2bf(c.y); v[6] = f2bf(c.z); v[7] = f2bf(c.w);
    *(uint4*)(xb + i8) = *(const uint4*)v;
  } else if (b < 2176) {        // w1t[e][h][c] = W1[e][c][h]
    int bp = b - 2048;
    int e = bp >> 4, tl = bp & 15;
    int c0 = (tl >> 2) * 64, h0 = (tl & 3) * 64;
    const float* src = W1 + (size_t)e * 65536;
#pragma unroll
    for (int p = 0; p < 4; ++p) {
      int r = p * 16 + (tid >> 4), d4 = (tid & 15) * 4;
      float4 v = *(const float4*)(src + (size_t)(c0 + r) * 256 + h0 + d4);
      T[r][d4] = v.x; T[r][d4 + 1] = v.y; T[r][d4 + 2] = v.z; T[r][d4 + 3] = v.w;
    }
    __syncthreads();
#pragma unroll
    for (int p = 0; p < 4; ++p) {
      int hr = p * 16 + (tid >> 4), c4 = (tid & 15) * 4;
      USH w[4];
#pragma unroll
      for (int j = 0; j < 4; ++j) w[j] = f2bf(T[c4 + j][hr]);
      *(uint2*)(w1t + (size_t)e * 65536 + (size_t)(h0 + hr) * 256 + c0 + c4) = *(const uint2*)w;
    }
  } else if (b < 2184) {        // wg1t[h][c] = Wg1[c][h]  (256x128 src)
    int bp = b - 2176;
    int c0 = (bp >> 1) * 64, h0 = (bp & 1) * 64;
#pragma unroll
    for (int p = 0; p < 4; ++p) {
      int r = p * 16 + (tid >> 4), d4 = (tid & 15) * 4;
      float4 v = *(const float4*)(Wg1 + (size_t)(c0 + r) * 128 + h0 + d4);
      T[r][d4] = v.x; T[r][d4 + 1] = v.y; T[r][d4 + 2] = v.z; T[r][d4 + 3] = v.w;
    }
    __syncthreads();
#pragma unroll
    for (int p = 0; p < 4; ++p) {
      int hr = p * 16 + (tid >> 4), c4 = (tid & 15) * 4;
      USH w[4];
#pragma unroll
      for (int j = 0; j < 4; ++j) w[j] = f2bf(T[c4 + j][hr]);
      *(uint2*)(wg1t + (size_t)(h0 + hr) * 256 + c0 + c4) = *(const uint2*)w;
    }
  } else if (b < 2312) {        // w2t[d][e*256+h] = W2[e][h][d]
    int bp = b - 2184;
    int e = bp >> 4, tl = bp & 15;
    int h0 = (tl >> 2) * 64, d0 = (tl & 3) * 64;
    const float* src = W2 + (size_t)e * 65536;
#pragma unroll
    for (int p = 0; p < 4; ++p) {
      int r = p * 16 + (tid >> 4), d4 = (tid & 15) * 4;
      float4 v = *(const float4*)(src + (size_t)(h0 + r) * 256 + d0 + d4);
      T[r][d4] = v.x; T[r][d4 + 1] = v.y; T[r][d4 + 2] = v.z; T[r][d4 + 3] = v.w;
    }
    __syncthreads();
#pragma unroll
    for (int p = 0; p < 4; ++p) {
      int dr = p * 16 + (tid >> 4), h4 = (tid & 15) * 4;
      USH w[4];
#pragma unroll
      for (int j = 0; j < 4; ++j) w[j] = f2bf(T[h4 + j][dr]);
      *(uint2*)(w2t + (size_t)(d0 + dr) * 2080 + e * 256 + h0 + h4) = *(const uint2*)w;
    }
  } else {                      // w2t bias cols 2048..2079 (tid = d)
    size_t base = (size_t)tid * 2080 + 2048;
#pragma unroll
    for (int p = 0; p < 8; ++p) {
      USH w[4];
#pragma unroll
      for (int j = 0; j < 4; ++j) {
        int e = p * 4 + j;
        w[j] = (e < 8) ? f2bf(b2[e * 256 + tid]) : (USH)0;
      }
      *(uint2*)(w2t + base + p * 4) = *(const uint2*)w;
    }
  }
}

// ---------------- gate: g = softmax(relu(x@Wg1+bg1)@Wg2+bg2) ----------------

__global__ __launch_bounds__(256) void k_gate(const USH* __restrict__ xb,
                                              const USH* __restrict__ wg1t,
                                              const float* __restrict__ bg1,
                                              const float* __restrict__ wg2,
                                              const float* __restrict__ bg2,
                                              float* __restrict__ g,
                                              USH* __restrict__ hw) {
  __shared__ __align__(16) USH As[64 * 32];
  __shared__ __align__(16) USH Bs[128 * 32];
  __shared__ float hg[64 * 129];
  __shared__ float bg1s[128];
  __shared__ float w2s[128 * 8];
  __shared__ float b2s[8];
  __shared__ float lg[64 * 8];

  int tid = threadIdx.x;
  int wave = tid >> 6, lane = tid & 63;
  int quad = lane >> 4, l16 = lane & 15;
  int rowBase = blockIdx.x * 64;

  for (int t = tid; t < 1024; t += 256) w2s[t] = wg2[t];
  if (tid < 8) b2s[tid] = bg2[tid];
  if (tid < 128) bg1s[tid] = bg1[tid];

  f32x4 acc[8] = {};
  for (int kt = 0; kt < 8; ++kt) {
    int kb = kt * 32;
    {
      int r = tid >> 2, kc = (tid & 3) * 8;
      gl2lds16(xb + (size_t)(rowBase + r) * 256 + kb + kc, As + (size_t)tid * 8);
    }
#pragma unroll
    for (int c = 0; c < 2; ++c) {
      int i = c * 256 + tid;
      int r = i >> 2, kc = (i & 3) * 8;
      gl2lds16(wg1t + (size_t)r * 256 + kb + kc, Bs + (size_t)i * 8);
    }
    __syncthreads();
    bf16x8 av = *(const bf16x8*)(As + (wave * 16 + l16) * 32 + quad * 8);
#pragma unroll
    for (int j = 0; j < 8; ++j) {
      bf16x8 bv = *(const bf16x8*)(Bs + (j * 16 + l16) * 32 + quad * 8);
      acc[j] = __builtin_amdgcn_mfma_f32_16x16x32_bf16(av, bv, acc[j], 0, 0, 0);
    }
    __syncthreads();
  }

#pragma unroll
  for (int j = 0; j < 8; ++j)
#pragma unroll
    for (int r = 0; r < 4; ++r) {
      int row = wave * 16 + quad * 4 + r;
      int col = j * 16 + l16;
      hg[row * 129 + col] = fmaxf(acc[j][r] + bg1s[col], 0.0f);
    }
  __syncthreads();

  {
    int row = tid >> 2, p = tid & 3;
    float s0 = b2s[p * 2], s1 = b2s[p * 2 + 1];
    for (int k = 0; k < 128; ++k) {
      float h = hg[row * 129 + k];
      s0 += h * w2s[k * 8 + p * 2];
      s1 += h * w2s[k * 8 + p * 2 + 1];
    }
    lg[row * 8 + p * 2] = s0;
    lg[row * 8 + p * 2 + 1] = s1;
  }
  __syncthreads();

  if (tid < 64) {
    float l[8];
    float m = -1e30f;
#pragma unroll
    for (int e = 0; e < 8; ++e) { l[e] = lg[tid * 8 + e]; m = fmaxf(m, l[e]); }
    float s = 0.0f;
#pragma unroll
    for (int e = 0; e < 8; ++e) { l[e] = expf(l[e] - m); s += l[e]; }
    float inv = 1.0f / s;
    size_t grow = rowBase + tid;
#pragma unroll
    for (int e = 0; e < 8; ++e) {
      float ge = l[e] * inv;
      g[grow * 8 + e] = ge;
      hw[grow * 2080 + 2048 + e] = f2bf(ge);
    }
#pragma unroll
    for (int z = 0; z < 24; ++z) hw[grow * 2080 + 2056 + z] = 0;
  }
}

// ---------------- stage 1: hw[:, e*256+h] = g[:,e]*relu(x@W1[e]+b1[e]) ----------------

__global__ __launch_bounds__(256) void k_stage1(const USH* __restrict__ xb,
                                                const USH* __restrict__ w1t,
                                                const float* __restrict__ b1,
                                                const float* __restrict__ g,
                                                USH* __restrict__ hw) {
  __shared__ __align__(16) USH As[128 * 32];
  __shared__ __align__(16) USH Bs[128 * 32];
  __shared__ float gs[128];
  __shared__ float b1s[128];

  int tid = threadIdx.x;
  int wave = tid >> 6, lane = tid & 63;
  int quad = lane >> 4, l16 = lane & 15;
  int wr = wave >> 1, wc = wave & 1;
  int rowBase = blockIdx.x * 128;
  int colBase = blockIdx.y * 128;
  int e = blockIdx.z;

  if (tid < 128) {
    gs[tid] = g[(size_t)(rowBase + tid) * 8 + e];
    b1s[tid] = b1[e * 256 + colBase + tid];
  }

  const USH* B = w1t + (size_t)e * 65536;

  f32x4 acc[4][4] = {};
  for (int kt = 0; kt < 8; ++kt) {
    int kb = kt * 32;
#pragma unroll
    for (int c = 0; c < 2; ++c) {
      int i = c * 256 + tid;
      int r = i >> 2, kc = (i & 3) * 8;
      gl2lds16(xb + (size_t)(rowBase + r) * 256 + kb + kc, As + (size_t)i * 8);
      gl2lds16(B + (size_t)(colBase + r) * 256 + kb + kc, Bs + (size_t)i * 8);
    }
    __syncthreads();
    bf16x8 av[4], bv[4];
#pragma unroll
    for (int i = 0; i < 4; ++i)
      av[i] = *(const bf16x8*)(As + (wr * 64 + i * 16 + l16) * 32 + quad * 8);
#pragma unroll
    for (int j = 0; j < 4; ++j)
      bv[j] = *(const bf16x8*)(Bs + (wc * 64 + j * 16 + l16) * 32 + quad * 8);
#pragma unroll
    for (int i = 0; i < 4; ++i)
#pragma unroll
      for (int j = 0; j < 4; ++j)
        acc[i][j] = __builtin_amdgcn_mfma_f32_16x16x32_bf16(av[i], bv[j], acc[i][j], 0, 0, 0);
    __syncthreads();
  }

#pragma unroll
  for (int i = 0; i < 4; ++i) {
#pragma unroll
    for (int r = 0; r < 4; ++r) {
      int rl = wr * 64 + i * 16 + quad * 4 + r;
      float gg = gs[rl];
      size_t grow = (size_t)(rowBase + rl);
#pragma unroll
      for (int j = 0; j < 4; ++j) {
        int cl = wc * 64 + j * 16 + l16;
        float v = fmaxf(acc[i][j][r] + b1s[cl], 0.0f) * gg;
        hw[grow * 2080 + e * 256 + colBase + cl] = f2bf(v);
      }
    }
  }
}

// ---------------- stage 2: out = hw @ w2t^T (K=2080 incl. g*b2 terms) ----------
// 64x64 tiles, grid (256,4) = 1024 blocks = 4 blocks/CU, direct fp32 stores.

__global__ __launch_bounds__(256) void k_stage2(const USH* __restrict__ hwm,
                                                const USH* __restrict__ w2t,
                                                float* __restrict__ out) {
  __shared__ __align__(16) USH As[64 * 32];
  __shared__ __align__(16) USH Bs[64 * 32];

  int tid = threadIdx.x;
  int wave = tid >> 6, lane = tid & 63;
  int quad = lane >> 4, l16 = lane & 15;
  int rowBase = blockIdx.x * 64;
  int colBase = blockIdx.y * 64;

  f32x4 acc[4] = {};
  for (int kt = 0; kt < 65; ++kt) {
    int kb = kt * 32;
    {
      int r = tid >> 2, kc = (tid & 3) * 8;
      gl2lds16(hwm + (size_t)(rowBase + r) * 2080 + kb + kc, As + (size_t)tid * 8);
      gl2lds16(w2t + (size_t)(colBase + r) * 2080 + kb + kc, Bs + (size_t)tid * 8);
    }
    __syncthreads();
    bf16x8 av = *(const bf16x8*)(As + (wave * 16 + l16) * 32 + quad * 8);
#pragma unroll
    for (int j = 0; j < 4; ++j) {
      bf16x8 bv = *(const bf16x8*)(Bs + (j * 16 + l16) * 32 + quad * 8);
      acc[j] = __builtin_amdgcn_mfma_f32_16x16x32_bf16(av, bv, acc[j], 0, 0, 0);
    }
    __syncthreads();
  }

#pragma unroll
  for (int j = 0; j < 4; ++j)
#pragma unroll
    for (int r = 0; r < 4; ++r) {
      int row = wave * 16 + quad * 4 + r;
      out[(size_t)(rowBase + row) * 256 + colBase + j * 16 + l16] = acc[j][r];
    }
}

// ---------------- launch ----------------

extern "C" void kernel_launch(void* const* d_in, const int* in_sizes, int n_in,
                              void* d_out, int out_size, void* d_ws, size_t ws_size,
                              hipStream_t stream) {
  const float* x   = (const float*)d_in[0];
  const float* Wg1 = (const float*)d_in[1];
  const float* bg1 = (const float*)d_in[2];
  const float* Wg2 = (const float*)d_in[3];
  const float* bg2 = (const float*)d_in[4];
  const float* W1  = (const float*)d_in[5];
  const float* b1  = (const float*)d_in[6];
  const float* W2  = (const float*)d_in[7];
  const float* b2  = (const float*)d_in[8];
  float* out = (float*)d_out;

  char* ws = (char*)d_ws;
  USH*   xb   = (USH*)(ws);
  USH*   w1t  = (USH*)(ws + 8388608);
  USH*   wg1t = (USH*)(ws + 9437184);
  USH*   w2t  = (USH*)(ws + 9502720);
  float* g    = (float*)(ws + 10567680);
  USH*   hw   = (USH*)(ws + 11091968);   // total 79,249,408 B

  hipLaunchKernelGGL(k_prep, dim3(2313), dim3(256), 0, stream,
                     x, Wg1, W1, W2, b2, xb, wg1t, w1t, w2t);
  hipLaunchKernelGGL(k_gate,   dim3(256),       dim3(256), 0, stream, xb, wg1t, bg1, Wg2, bg2, g, hw);
  hipLaunchKernelGGL(k_stage1, dim3(128, 2, 8), dim3(256), 0, stream, xb, w1t, b1, g, hw);
  hipLaunchKernelGGL(k_stage2, dim3(256, 4),    dim3(256), 0, stream, hw, w2t, out);
}